// Round 9
// baseline (651.934 us; speedup 1.0000x reference)
//
#include <hip/hip_runtime.h>
#include <hip/hip_bf16.h>

typedef __bf16 bf16_t;
typedef __attribute__((ext_vector_type(8))) __bf16 bf16x8;
typedef __attribute__((ext_vector_type(4))) float f32x4;

// ---------------- prep kernels (tiny, unchanged) ----------------
__global__ void prep_wvp(const float* __restrict__ Wv, const float* __restrict__ Wp,
                         const float* __restrict__ bp, const float* __restrict__ bv,
                         float* __restrict__ Wvp, float* __restrict__ bvp) {
  const int i = blockIdx.x;
  const int j = threadIdx.x;
  float a = 0.f;
  for (int d = 0; d < 512; ++d) a += Wv[i * 512 + d] * Wp[d * 256 + j];
  Wvp[i * 256 + j] = a;
  if (j == 0) {
    float b = 0.f;
    for (int d = 0; d < 512; ++d) b += Wv[i * 512 + d] * bp[d];
    bvp[i] = b + bv[i];
  }
}

// Packed-B layout (harness-verified rounds 4/7/8), N x K row-major source:
//   B[n][k] -> Bp[(((n>>4)*(K/32) + (k>>5))*64 + ((k>>3)&3)*16 + (n&15))*8 + (k&7)]
__global__ void prep_wc(const float* __restrict__ Wo, const float* __restrict__ bo,
                        const float* __restrict__ Wvp, const float* __restrict__ bvp,
                        bf16_t* __restrict__ Wc, float* __restrict__ bcomb) {
  const int o = blockIdx.x;
  const int j = threadIdx.x;
  float a = 0.f;
  for (int i = 0; i < 512; ++i) a += Wo[o * 512 + i] * Wvp[i * 256 + j];
  const int g = o >> 4, rr = o & 15, t = j >> 5, q = (j >> 3) & 3, e = j & 7;
  Wc[((((size_t)g * 8 + t) * 64) + q * 16 + rr) * 8 + e] = (bf16_t)a;  // S=8
  if (j == 0) {
    float b = 0.f;
    for (int i = 0; i < 512; ++i) b += Wo[o * 512 + i] * bvp[i];
    bcomb[o] = b + bo[o];
  }
}

__global__ void prep_cast(const float* __restrict__ W1, const float* __restrict__ W2,
                          bf16_t* __restrict__ W1b, bf16_t* __restrict__ W2b) {
  const int idx = (blockIdx.x * 256 + threadIdx.x) * 8;
  const float* s;
  bf16_t* d;
  if (idx < 524288) {  // W1: K=512, S=16
    const int o = idx >> 9, k = idx & 511;
    const int g = o >> 4, rr = o & 15, t = k >> 5, q = (k >> 3) & 3;
    s = W1 + idx;
    d = W1b + ((((size_t)g * 16 + t) * 64) + q * 16 + rr) * 8;
  } else {             // W2: K=1024, S=32
    const int i2 = idx - 524288;
    const int o = i2 >> 10, k = i2 & 1023;
    const int g = o >> 4, rr = o & 15, t = k >> 5, q = (k >> 3) & 3;
    s = W2 + i2;
    d = W2b + ((((size_t)g * 32 + t) * 64) + q * 16 + rr) * 8;
  }
  float4 u0 = *(const float4*)s;
  float4 u1 = *(const float4*)(s + 4);
  bf16x8 v;
  v[0] = (bf16_t)u0.x; v[1] = (bf16_t)u0.y; v[2] = (bf16_t)u0.z; v[3] = (bf16_t)u0.w;
  v[4] = (bf16_t)u1.x; v[5] = (bf16_t)u1.y; v[6] = (bf16_t)u1.z; v[7] = (bf16_t)u1.w;
  *(bf16x8*)d = v;
}

// ---------------- fully fused block kernel ----------------
// Block = 64 rows of the batch; 512 threads = 8 waves (wr=w>>2: 32-row half,
// wc=w&3: 128-col quarter). All GEMMs: acc[2][8] (64 VGPR), af[2], 8 B-frags,
// 16 MFMA/step -- the proven round-8 shape. A-operands live in LDS (A-layout:
// 16-row windows of 1KB, slot=rr*4+(c^((rr>>1)&3)), verified conflict-free
// ds_read_b128). B streams from packed weights (L2-resident, 2.3MB/XCD).
//
// Phases (per block):  [x and h NEVER touch HBM]
//  P0: stage pert (64x256 f32->bf16) -> lH     (A-layout)
//  P1: attn GEMM (K=256, Wc) -> +bcomb +cell(HBM) -> LN1 -> x -> lX (b16 writes)
//  P2a: h0 = gelu(x @ W1[0:512]^T + b1)  -> lH   (K=512)
//  P3a: acc3 += h0 @ W2[:,0:512]^T               (K-half 1)
//  P2b: h1 = gelu(x @ W1[512:1024]^T)    -> lH   (after P3a barrier)
//  P3b: acc3 += h1 @ W2[:,512:1024]^T            (K-half 2)
//  P4: out = LN2(acc3 + b2 + x) -> fp32 HBM
// Barrier-free K-loops (A resident); ~8 __syncthreads total per block.
// LDS: lX 64KB + lH 64KB + LN scratch 2KB = 130KB -> 1 block/CU, 8 waves.

__device__ __forceinline__ int alay(int row, int k) {
  const int rr = row & 15;
  const int c = (k >> 3) & 3;
  return (((k >> 5) & 15) * 4 + (row >> 4)) * 512 +
         (rr * 4 + (c ^ ((rr >> 1) & 3))) * 8 + (k & 7);
}

template <int STEPS>
__device__ __forceinline__ void kloop8(const bf16_t* __restrict__ lA_,
                                       const bf16_t* __restrict__ Bp,
                                       int g0, int SB, int soff,
                                       int fRd, int awin, int lane,
                                       f32x4 (&acc)[2][8]) {
  auto bfrag = [&](int j, int s) {
    return *(const bf16x8*)(Bp + ((size_t)((g0 + j) * SB + (soff + s)) * 64 + lane) * 8);
  };
  bf16x8 bA[4], bB[4];
#pragma unroll
  for (int j = 0; j < 4; ++j) bA[j] = bfrag(j, 0);
#pragma unroll 2
  for (int s = 0; s < STEPS; ++s) {
#pragma unroll
    for (int j = 0; j < 4; ++j) bB[j] = bfrag(4 + j, s);
    bf16x8 af[2];
#pragma unroll
    for (int i = 0; i < 2; ++i)
      af[i] = *(const bf16x8*)&lA_[(s * 4 + awin + i) * 512 + fRd];
    __builtin_amdgcn_s_setprio(1);
#pragma unroll
    for (int j = 0; j < 4; ++j)
#pragma unroll
      for (int i = 0; i < 2; ++i)
        acc[i][j] = __builtin_amdgcn_mfma_f32_16x16x32_bf16(af[i], bA[j], acc[i][j], 0, 0, 0);
    __builtin_amdgcn_s_setprio(0);
    if (s + 1 < STEPS) {
#pragma unroll
      for (int j = 0; j < 4; ++j) bA[j] = bfrag(j, s + 1);
    }
    __builtin_amdgcn_s_setprio(1);
#pragma unroll
    for (int j = 0; j < 4; ++j)
#pragma unroll
      for (int i = 0; i < 2; ++i)
        acc[i][4 + j] = __builtin_amdgcn_mfma_f32_16x16x32_bf16(af[i], bB[j], acc[i][4 + j], 0, 0, 0);
    __builtin_amdgcn_s_setprio(0);
  }
}

__global__ __launch_bounds__(512, 1) void fused_block(
    const float* __restrict__ pert, const bf16_t* __restrict__ Wc,
    const float* __restrict__ bcomb, const float* __restrict__ cell,
    const float* __restrict__ g1, const float* __restrict__ be1,
    const bf16_t* __restrict__ W1b, const float* __restrict__ b1,
    const bf16_t* __restrict__ W2b, const float* __restrict__ b2,
    const float* __restrict__ g2, const float* __restrict__ be2,
    float* __restrict__ out) {

  __shared__ __align__(16) bf16_t lX[64 * 512];   // 64 KB: x
  __shared__ __align__(16) bf16_t lH[64 * 512];   // 64 KB: pert, then h halves
  __shared__ float rs[4][64];
  __shared__ float rss[4][64];

  const int t = threadIdx.x;
  const int m0 = blockIdx.x * 64;
  const int lane = t & 63;
  const int w = t >> 6;
  const int wr = w >> 2;          // rows [32wr, 32wr+32)
  const int wc = w & 3;           // cols [128wc, 128wc+128)
  const int r = lane & 15;
  const int q = lane >> 4;
  const int qs = q ^ ((r >> 1) & 3);
  const int fRd = r * 32 + qs * 8;
  const int awin = 2 * wr;

  // ---- P0: stage pert (64 x 256 fp32 -> bf16, A-layout) into lH ----
#pragma unroll
  for (int u = 0; u < 4; ++u) {
    const int g = u * 512 + t;      // slot 0..2047
    const int row = g >> 5;
    const int c = g & 31;           // k-chunk (k = 8c < 256)
    const float* src = pert + (size_t)(m0 + row) * 256 + c * 8;
    float4 u0 = *(const float4*)src;
    float4 u1 = *(const float4*)(src + 4);
    bf16x8 v;
    v[0] = (bf16_t)u0.x; v[1] = (bf16_t)u0.y; v[2] = (bf16_t)u0.z; v[3] = (bf16_t)u0.w;
    v[4] = (bf16_t)u1.x; v[5] = (bf16_t)u1.y; v[6] = (bf16_t)u1.z; v[7] = (bf16_t)u1.w;
    *(bf16x8*)&lH[alay(row, c * 8)] = v;
  }
  __syncthreads();

  f32x4 acc1[2][8];
#pragma unroll
  for (int i = 0; i < 2; ++i)
#pragma unroll
    for (int j = 0; j < 8; ++j)
#pragma unroll
      for (int p = 0; p < 4; ++p) acc1[i][j][p] = 0.f;

  // ---- P1: attn GEMM (K=256) ----
  kloop8<8>(lH, Wc, 8 * wc, 8, 0, fRd, awin, lane, acc1);

  {  // +bcomb +cell, LN1 -> x in lX
    float s_[2][4], ss_[2][4];
#pragma unroll
    for (int i = 0; i < 2; ++i)
#pragma unroll
      for (int p = 0; p < 4; ++p) { s_[i][p] = 0.f; ss_[i][p] = 0.f; }
    float bb[8];
#pragma unroll
    for (int j = 0; j < 8; ++j) bb[j] = bcomb[128 * wc + 16 * j + r];
#pragma unroll
    for (int i = 0; i < 2; ++i)
#pragma unroll
      for (int p = 0; p < 4; ++p) {
        const int rowl = 32 * wr + 16 * i + 4 * q + p;
#pragma unroll
        for (int j = 0; j < 8; ++j) {
          const int col = 128 * wc + 16 * j + r;
          float v = acc1[i][j][p] + bb[j] + cell[(size_t)(m0 + rowl) * 512 + col];
          acc1[i][j][p] = v;
          s_[i][p] += v;
          ss_[i][p] += v * v;
        }
      }
#pragma unroll
    for (int m = 1; m <= 8; m <<= 1)
#pragma unroll
      for (int i = 0; i < 2; ++i)
#pragma unroll
        for (int p = 0; p < 4; ++p) {
          s_[i][p] += __shfl_xor(s_[i][p], m);
          ss_[i][p] += __shfl_xor(ss_[i][p], m);
        }
    if (r == 0) {
#pragma unroll
      for (int i = 0; i < 2; ++i)
#pragma unroll
        for (int p = 0; p < 4; ++p) {
          const int rowl = 32 * wr + 16 * i + 4 * q + p;
          rs[wc][rowl] = s_[i][p];
          rss[wc][rowl] = ss_[i][p];
        }
    }
    __syncthreads();
    float mu[2][4], inv[2][4];
#pragma unroll
    for (int i = 0; i < 2; ++i)
#pragma unroll
      for (int p = 0; p < 4; ++p) {
        const int rowl = 32 * wr + 16 * i + 4 * q + p;
        float tS = rs[0][rowl] + rs[1][rowl] + rs[2][rowl] + rs[3][rowl];
        float tQ = rss[0][rowl] + rss[1][rowl] + rss[2][rowl] + rss[3][rowl];
        float m_ = tS * (1.0f / 512.0f);
        float v_ = tQ * (1.0f / 512.0f) - m_ * m_;
        mu[i][p] = m_;
        inv[i][p] = rsqrtf(v_ + 1e-5f);
      }
    float ga[8], be[8];
#pragma unroll
    for (int j = 0; j < 8; ++j) {
      ga[j] = g1[128 * wc + 16 * j + r];
      be[j] = be1[128 * wc + 16 * j + r];
    }
#pragma unroll
    for (int i = 0; i < 2; ++i)
#pragma unroll
      for (int p = 0; p < 4; ++p) {
        const int rowl = 32 * wr + 16 * i + 4 * q + p;
#pragma unroll
        for (int j = 0; j < 8; ++j) {
          const int col = 128 * wc + 16 * j + r;
          float v = (acc1[i][j][p] - mu[i][p]) * inv[i][p] * ga[j] + be[j];
          lX[alay(rowl, col)] = (bf16_t)v;
        }
      }
  }
  __syncthreads();  // x resident; pert dead

  // ---- FFN: two h-halves interleaved with out K-halves ----
  f32x4 acc3[2][8];
#pragma unroll
  for (int i = 0; i < 2; ++i)
#pragma unroll
    for (int j = 0; j < 8; ++j)
#pragma unroll
      for (int p = 0; p < 4; ++p) acc3[i][j][p] = 0.f;

  for (int hh = 0; hh < 2; ++hh) {
#pragma unroll
    for (int i = 0; i < 2; ++i)
#pragma unroll
      for (int j = 0; j < 8; ++j)
#pragma unroll
        for (int p = 0; p < 4; ++p) acc1[i][j][p] = 0.f;
    // P2: h-half = x @ W1[512hh : 512hh+512]^T   (K=512)
    kloop8<16>(lX, W1b, 32 * hh + 8 * wc, 16, 0, fRd, awin, lane, acc1);
    {  // bias + exact GELU -> lH (A-layout, k = local col)
      float bb1[8];
#pragma unroll
      for (int j = 0; j < 8; ++j) bb1[j] = b1[512 * hh + 128 * wc + 16 * j + r];
#pragma unroll
      for (int i = 0; i < 2; ++i)
#pragma unroll
        for (int p = 0; p < 4; ++p) {
          const int rowl = 32 * wr + 16 * i + 4 * q + p;
#pragma unroll
          for (int j = 0; j < 8; ++j) {
            const int col = 128 * wc + 16 * j + r;
            float v = acc1[i][j][p] + bb1[j];
            float g = 0.5f * v * (1.0f + erff(v * 0.70710678118654752f));
            lH[alay(rowl, col)] = (bf16_t)g;
          }
        }
    }
    __syncthreads();  // h-half resident everywhere
    // P3: acc3 += h-half @ W2[:, 512hh : 512hh+512]^T
    kloop8<16>(lH, W2b, 8 * wc, 32, 16 * hh, fRd, awin, lane, acc3);
    if (hh == 0) __syncthreads();  // all reads of h0 done before h1 overwrite
  }

  // ---- P4: LN2(acc3 + b2 + x) -> fp32 out ----
  {
    float s_[2][4], ss_[2][4];
#pragma unroll
    for (int i = 0; i < 2; ++i)
#pragma unroll
      for (int p = 0; p < 4; ++p) { s_[i][p] = 0.f; ss_[i][p] = 0.f; }
    float bb2[8];
#pragma unroll
    for (int j = 0; j < 8; ++j) bb2[j] = b2[128 * wc + 16 * j + r];
#pragma unroll
    for (int i = 0; i < 2; ++i)
#pragma unroll
      for (int p = 0; p < 4; ++p) {
        const int rowl = 32 * wr + 16 * i + 4 * q + p;
#pragma unroll
        for (int j = 0; j < 8; ++j) {
          const int col = 128 * wc + 16 * j + r;
          float v = acc3[i][j][p] + bb2[j] + (float)lX[alay(rowl, col)];
          acc3[i][j][p] = v;
          s_[i][p] += v;
          ss_[i][p] += v * v;
        }
      }
#pragma unroll
    for (int m = 1; m <= 8; m <<= 1)
#pragma unroll
      for (int i = 0; i < 2; ++i)
#pragma unroll
        for (int p = 0; p < 4; ++p) {
          s_[i][p] += __shfl_xor(s_[i][p], m);
          ss_[i][p] += __shfl_xor(ss_[i][p], m);
        }
    __syncthreads();  // rs/rss free for reuse
    if (r == 0) {
#pragma unroll
      for (int i = 0; i < 2; ++i)
#pragma unroll
        for (int p = 0; p < 4; ++p) {
          const int rowl = 32 * wr + 16 * i + 4 * q + p;
          rs[wc][rowl] = s_[i][p];
          rss[wc][rowl] = ss_[i][p];
        }
    }
    __syncthreads();
    float mu[2][4], inv[2][4];
#pragma unroll
    for (int i = 0; i < 2; ++i)
#pragma unroll
      for (int p = 0; p < 4; ++p) {
        const int rowl = 32 * wr + 16 * i + 4 * q + p;
        float tS = rs[0][rowl] + rs[1][rowl] + rs[2][rowl] + rs[3][rowl];
        float tQ = rss[0][rowl] + rss[1][rowl] + rss[2][rowl] + rss[3][rowl];
        float m_ = tS * (1.0f / 512.0f);
        float v_ = tQ * (1.0f / 512.0f) - m_ * m_;
        mu[i][p] = m_;
        inv[i][p] = rsqrtf(v_ + 1e-5f);
      }
    float ga[8], be[8];
#pragma unroll
    for (int j = 0; j < 8; ++j) {
      ga[j] = g2[128 * wc + 16 * j + r];
      be[j] = be2[128 * wc + 16 * j + r];
    }
#pragma unroll
    for (int i = 0; i < 2; ++i)
#pragma unroll
      for (int p = 0; p < 4; ++p) {
        const int rowl = 32 * wr + 16 * i + 4 * q + p;
#pragma unroll
        for (int j = 0; j < 8; ++j) {
          const int col = 128 * wc + 16 * j + r;
          out[(size_t)(m0 + rowl) * 512 + col] =
              (acc3[i][j][p] - mu[i][p]) * inv[i][p] * ga[j] + be[j];
        }
      }
  }
}

extern "C" void kernel_launch(void* const* d_in, const int* in_sizes, int n_in,
                              void* d_out, int out_size, void* d_ws, size_t ws_size,
                              hipStream_t stream) {
  const float* cell = (const float*)d_in[0];
  const float* pert = (const float*)d_in[1];
  const float* Wp   = (const float*)d_in[2];
  const float* bp   = (const float*)d_in[3];
  // d_in[4..7] = Wq,bq,Wk,bk: dead (softmax over a single key == 1 -> attn = v)
  const float* Wv   = (const float*)d_in[8];
  const float* bv   = (const float*)d_in[9];
  const float* Wo   = (const float*)d_in[10];
  const float* bo   = (const float*)d_in[11];
  const float* g1   = (const float*)d_in[12];
  const float* be1  = (const float*)d_in[13];
  const float* g2   = (const float*)d_in[14];
  const float* be2  = (const float*)d_in[15];
  const float* W1   = (const float*)d_in[16];
  const float* b1   = (const float*)d_in[17];
  const float* W2   = (const float*)d_in[18];
  const float* b2   = (const float*)d_in[19];

  char* ws = (char*)d_ws;
  float*  Wvp   = (float*)(ws + 0);          // 512*256*4   = 524288
  float*  bvp   = (float*)(ws + 524288);     // 512*4 (pad) = 2048
  float*  bcomb = (float*)(ws + 526336);     // 512*4 (pad) = 2048
  bf16_t* Wc    = (bf16_t*)(ws + 528384);    // 512*256*2   = 262144 (packed)
  bf16_t* W1b   = (bf16_t*)(ws + 790528);    // 1024*512*2  = 1048576 (packed)
  bf16_t* W2b   = (bf16_t*)(ws + 1839104);   // 512*1024*2  = 1048576 (packed)
  (void)in_sizes; (void)n_in; (void)out_size; (void)ws_size;

  prep_wvp<<<512, 256, 0, stream>>>(Wv, Wp, bp, bv, Wvp, bvp);
  prep_wc<<<512, 256, 0, stream>>>(Wo, bo, Wvp, bvp, Wc, bcomb);
  prep_cast<<<512, 256, 0, stream>>>(W1, W2, W1b, W2b);

  fused_block<<<1024, 512, 0, stream>>>(pert, Wc, bcomb, cell, g1, be1,
                                        W1b, b1, W2b, b2, g2, be2,
                                        (float*)d_out);
}

// Round 10
// 628.748 us; speedup vs baseline: 1.0369x; 1.0369x over previous
//
#include <hip/hip_runtime.h>
#include <hip/hip_bf16.h>

typedef __bf16 bf16_t;
typedef __attribute__((ext_vector_type(8))) __bf16 bf16x8;
typedef __attribute__((ext_vector_type(4))) float f32x4;

// ---------------- prep kernels (tiny, unchanged) ----------------
__global__ void prep_wvp(const float* __restrict__ Wv, const float* __restrict__ Wp,
                         const float* __restrict__ bp, const float* __restrict__ bv,
                         float* __restrict__ Wvp, float* __restrict__ bvp) {
  const int i = blockIdx.x;
  const int j = threadIdx.x;
  float a = 0.f;
  for (int d = 0; d < 512; ++d) a += Wv[i * 512 + d] * Wp[d * 256 + j];
  Wvp[i * 256 + j] = a;
  if (j == 0) {
    float b = 0.f;
    for (int d = 0; d < 512; ++d) b += Wv[i * 512 + d] * bp[d];
    bvp[i] = b + bv[i];
  }
}

// Packed-B layout (harness-verified rounds 4/7/8/9), N x K row-major source:
//   B[n][k] -> Bp[(((n>>4)*(K/32) + (k>>5))*64 + ((k>>3)&3)*16 + (n&15))*8 + (k&7)]
__global__ void prep_wc(const float* __restrict__ Wo, const float* __restrict__ bo,
                        const float* __restrict__ Wvp, const float* __restrict__ bvp,
                        bf16_t* __restrict__ Wc, float* __restrict__ bcomb) {
  const int o = blockIdx.x;
  const int j = threadIdx.x;
  float a = 0.f;
  for (int i = 0; i < 512; ++i) a += Wo[o * 512 + i] * Wvp[i * 256 + j];
  const int g = o >> 4, rr = o & 15, t = j >> 5, q = (j >> 3) & 3, e = j & 7;
  Wc[((((size_t)g * 8 + t) * 64) + q * 16 + rr) * 8 + e] = (bf16_t)a;  // S=8
  if (j == 0) {
    float b = 0.f;
    for (int i = 0; i < 512; ++i) b += Wo[o * 512 + i] * bvp[i];
    bcomb[o] = b + bo[o];
  }
}

__global__ void prep_cast(const float* __restrict__ W1, const float* __restrict__ W2,
                          bf16_t* __restrict__ W1b, bf16_t* __restrict__ W2b) {
  const int idx = (blockIdx.x * 256 + threadIdx.x) * 8;
  const float* s;
  bf16_t* d;
  if (idx < 524288) {  // W1: K=512, S=16
    const int o = idx >> 9, k = idx & 511;
    const int g = o >> 4, rr = o & 15, t = k >> 5, q = (k >> 3) & 3;
    s = W1 + idx;
    d = W1b + ((((size_t)g * 16 + t) * 64) + q * 16 + rr) * 8;
  } else {             // W2: K=1024, S=32
    const int i2 = idx - 524288;
    const int o = i2 >> 10, k = i2 & 1023;
    const int g = o >> 4, rr = o & 15, t = k >> 5, q = (k >> 3) & 3;
    s = W2 + i2;
    d = W2b + ((((size_t)g * 32 + t) * 64) + q * 16 + rr) * 8;
  }
  float4 u0 = *(const float4*)s;
  float4 u1 = *(const float4*)(s + 4);
  bf16x8 v;
  v[0] = (bf16_t)u0.x; v[1] = (bf16_t)u0.y; v[2] = (bf16_t)u0.z; v[3] = (bf16_t)u0.w;
  v[4] = (bf16_t)u1.x; v[5] = (bf16_t)u1.y; v[6] = (bf16_t)u1.z; v[7] = (bf16_t)u1.w;
  *(bf16x8*)d = v;
}

// ---------------- fully fused block kernel ----------------
// ROUND-10: round 9's fusion kept h/x off HBM (validated) but spilled:
// acc1[2][8]+acc3[2][8] = 128 AGPR + 128 VGPR = exactly the 256-reg cap
// (2 waves/SIMD), so bA/bB/af/addressing spilled -> +216MB scratch writes,
// 393us. Fix: h processed in FOUR 256-col quarters -- P2q uses accq[2][4]
// (32 regs, wave-tile 32x64), so peak acc liveness = 64(acc3)+32(accq)=96.
// B-bytes/MFMA unchanged (512B). LDS: lX 64KB + lH 32KB + 2KB = 98KB.
//
// Phases: P0 pert->lH | P1 attn K=256 ->LN1-> lX | 4x { P2q h_q=gelu(x@W1q)
// ->lH ; P3q acc3 += h_q@W2q } | P4 LN2 -> out.

__device__ __forceinline__ int alay(int row, int k) {
  const int rr = row & 15;
  const int c = (k >> 3) & 3;
  return (((k >> 5) & 15) * 4 + (row >> 4)) * 512 +
         (rr * 4 + (c ^ ((rr >> 1) & 3))) * 8 + (k & 7);
}

template <int STEPS, int NJ>
__device__ __forceinline__ void kloop(const bf16_t* __restrict__ lA_,
                                      const bf16_t* __restrict__ Bp,
                                      int g0, int SB, int soff,
                                      int fRd, int awin, int lane,
                                      f32x4 (&acc)[2][NJ]) {
  constexpr int H = NJ / 2;
  auto bfrag = [&](int j, int s) {
    return *(const bf16x8*)(Bp + ((size_t)((g0 + j) * SB + (soff + s)) * 64 + lane) * 8);
  };
  bf16x8 bA[H], bB[H];
#pragma unroll
  for (int j = 0; j < H; ++j) bA[j] = bfrag(j, 0);
#pragma unroll 2
  for (int s = 0; s < STEPS; ++s) {
#pragma unroll
    for (int j = 0; j < H; ++j) bB[j] = bfrag(H + j, s);
    bf16x8 af[2];
#pragma unroll
    for (int i = 0; i < 2; ++i)
      af[i] = *(const bf16x8*)&lA_[(s * 4 + awin + i) * 512 + fRd];
    __builtin_amdgcn_s_setprio(1);
#pragma unroll
    for (int j = 0; j < H; ++j)
#pragma unroll
      for (int i = 0; i < 2; ++i)
        acc[i][j] = __builtin_amdgcn_mfma_f32_16x16x32_bf16(af[i], bA[j], acc[i][j], 0, 0, 0);
    __builtin_amdgcn_s_setprio(0);
    if (s + 1 < STEPS) {
#pragma unroll
      for (int j = 0; j < H; ++j) bA[j] = bfrag(j, s + 1);
    }
    __builtin_amdgcn_s_setprio(1);
#pragma unroll
    for (int j = 0; j < H; ++j)
#pragma unroll
      for (int i = 0; i < 2; ++i)
        acc[i][H + j] = __builtin_amdgcn_mfma_f32_16x16x32_bf16(af[i], bB[j], acc[i][H + j], 0, 0, 0);
    __builtin_amdgcn_s_setprio(0);
  }
}

__global__ __launch_bounds__(512, 1) void fused_block(
    const float* __restrict__ pert, const bf16_t* __restrict__ Wc,
    const float* __restrict__ bcomb, const float* __restrict__ cell,
    const float* __restrict__ g1, const float* __restrict__ be1,
    const bf16_t* __restrict__ W1b, const float* __restrict__ b1,
    const bf16_t* __restrict__ W2b, const float* __restrict__ b2,
    const float* __restrict__ g2, const float* __restrict__ be2,
    float* __restrict__ out) {

  __shared__ __align__(16) bf16_t lX[64 * 512];   // 64 KB: x (A-layout, K=512)
  __shared__ __align__(16) bf16_t lH[64 * 256];   // 32 KB: pert, then h quarters
  __shared__ float rs[4][64];
  __shared__ float rss[4][64];

  const int t = threadIdx.x;
  const int m0 = blockIdx.x * 64;
  const int lane = t & 63;
  const int w = t >> 6;
  const int wr = w >> 2;          // rows [32wr, 32wr+32)
  const int wc = w & 3;
  const int r = lane & 15;
  const int q = lane >> 4;
  const int qs = q ^ ((r >> 1) & 3);
  const int fRd = r * 32 + qs * 8;
  const int awin = 2 * wr;

  // ---- P0: stage pert (64 x 256 fp32 -> bf16, A-layout) into lH ----
#pragma unroll
  for (int u = 0; u < 4; ++u) {
    const int g = u * 512 + t;      // slot 0..2047
    const int row = g >> 5;
    const int c = g & 31;
    const float* src = pert + (size_t)(m0 + row) * 256 + c * 8;
    float4 u0 = *(const float4*)src;
    float4 u1 = *(const float4*)(src + 4);
    bf16x8 v;
    v[0] = (bf16_t)u0.x; v[1] = (bf16_t)u0.y; v[2] = (bf16_t)u0.z; v[3] = (bf16_t)u0.w;
    v[4] = (bf16_t)u1.x; v[5] = (bf16_t)u1.y; v[6] = (bf16_t)u1.z; v[7] = (bf16_t)u1.w;
    *(bf16x8*)&lH[alay(row, c * 8)] = v;
  }
  __syncthreads();

  // ---- P1: attn GEMM (K=256), cols [128wc,+128) ----
  {
    f32x4 acc1[2][8];
#pragma unroll
    for (int i = 0; i < 2; ++i)
#pragma unroll
      for (int j = 0; j < 8; ++j)
#pragma unroll
        for (int p = 0; p < 4; ++p) acc1[i][j][p] = 0.f;
    kloop<8, 8>(lH, Wc, 8 * wc, 8, 0, fRd, awin, lane, acc1);

    // +bcomb +cell, LN1 -> x in lX
    float s_[2][4], ss_[2][4];
#pragma unroll
    for (int i = 0; i < 2; ++i)
#pragma unroll
      for (int p = 0; p < 4; ++p) { s_[i][p] = 0.f; ss_[i][p] = 0.f; }
    float bb[8];
#pragma unroll
    for (int j = 0; j < 8; ++j) bb[j] = bcomb[128 * wc + 16 * j + r];
#pragma unroll
    for (int i = 0; i < 2; ++i)
#pragma unroll
      for (int p = 0; p < 4; ++p) {
        const int rowl = 32 * wr + 16 * i + 4 * q + p;
#pragma unroll
        for (int j = 0; j < 8; ++j) {
          const int col = 128 * wc + 16 * j + r;
          float v = acc1[i][j][p] + bb[j] + cell[(size_t)(m0 + rowl) * 512 + col];
          acc1[i][j][p] = v;
          s_[i][p] += v;
          ss_[i][p] += v * v;
        }
      }
#pragma unroll
    for (int m = 1; m <= 8; m <<= 1)
#pragma unroll
      for (int i = 0; i < 2; ++i)
#pragma unroll
        for (int p = 0; p < 4; ++p) {
          s_[i][p] += __shfl_xor(s_[i][p], m);
          ss_[i][p] += __shfl_xor(ss_[i][p], m);
        }
    if (r == 0) {
#pragma unroll
      for (int i = 0; i < 2; ++i)
#pragma unroll
        for (int p = 0; p < 4; ++p) {
          const int rowl = 32 * wr + 16 * i + 4 * q + p;
          rs[wc][rowl] = s_[i][p];
          rss[wc][rowl] = ss_[i][p];
        }
    }
    __syncthreads();
    float mu[2][4], inv[2][4];
#pragma unroll
    for (int i = 0; i < 2; ++i)
#pragma unroll
      for (int p = 0; p < 4; ++p) {
        const int rowl = 32 * wr + 16 * i + 4 * q + p;
        float tS = rs[0][rowl] + rs[1][rowl] + rs[2][rowl] + rs[3][rowl];
        float tQ = rss[0][rowl] + rss[1][rowl] + rss[2][rowl] + rss[3][rowl];
        float m_ = tS * (1.0f / 512.0f);
        float v_ = tQ * (1.0f / 512.0f) - m_ * m_;
        mu[i][p] = m_;
        inv[i][p] = rsqrtf(v_ + 1e-5f);
      }
    float ga[8], be[8];
#pragma unroll
    for (int j = 0; j < 8; ++j) {
      ga[j] = g1[128 * wc + 16 * j + r];
      be[j] = be1[128 * wc + 16 * j + r];
    }
#pragma unroll
    for (int i = 0; i < 2; ++i)
#pragma unroll
      for (int p = 0; p < 4; ++p) {
        const int rowl = 32 * wr + 16 * i + 4 * q + p;
#pragma unroll
        for (int j = 0; j < 8; ++j) {
          const int col = 128 * wc + 16 * j + r;
          float v = (acc1[i][j][p] - mu[i][p]) * inv[i][p] * ga[j] + be[j];
          lX[alay(rowl, col)] = (bf16_t)v;
        }
      }
  }
  __syncthreads();  // x resident; pert dead

  // ---- FFN: four h-quarters; acc3 peak-liveness overlap only with accq(32) ----
  f32x4 acc3[2][8];
#pragma unroll
  for (int i = 0; i < 2; ++i)
#pragma unroll
    for (int j = 0; j < 8; ++j)
#pragma unroll
      for (int p = 0; p < 4; ++p) acc3[i][j][p] = 0.f;

  for (int qh = 0; qh < 4; ++qh) {
    {
      f32x4 accq[2][4];
#pragma unroll
      for (int i = 0; i < 2; ++i)
#pragma unroll
        for (int j = 0; j < 4; ++j)
#pragma unroll
          for (int p = 0; p < 4; ++p) accq[i][j][p] = 0.f;
      // P2q: h_q = x @ W1[256qh : 256qh+256]^T  (K=512; wave cols [64wc,+64))
      kloop<16, 4>(lX, W1b, 16 * qh + 4 * wc, 16, 0, fRd, awin, lane, accq);
      // bias + exact GELU -> lH (A-layout, local col 0..255)
      float bb1[4];
#pragma unroll
      for (int j = 0; j < 4; ++j) bb1[j] = b1[256 * qh + 64 * wc + 16 * j + r];
#pragma unroll
      for (int i = 0; i < 2; ++i)
#pragma unroll
        for (int p = 0; p < 4; ++p) {
          const int rowl = 32 * wr + 16 * i + 4 * q + p;
#pragma unroll
          for (int j = 0; j < 4; ++j) {
            const int col = 64 * wc + 16 * j + r;
            float v = accq[i][j][p] + bb1[j];
            float g = 0.5f * v * (1.0f + erff(v * 0.70710678118654752f));
            lH[alay(rowl, col)] = (bf16_t)g;
          }
        }
    }
    __syncthreads();  // h_q resident everywhere
    // P3q: acc3 += h_q @ W2[:, 256qh : 256qh+256]^T  (K=256)
    kloop<8, 8>(lH, W2b, 8 * wc, 32, 8 * qh, fRd, awin, lane, acc3);
    __syncthreads();  // all reads of h_q done before overwrite
  }

  // ---- P4: LN2(acc3 + b2 + x) -> fp32 out ----
  {
    float s_[2][4], ss_[2][4];
#pragma unroll
    for (int i = 0; i < 2; ++i)
#pragma unroll
      for (int p = 0; p < 4; ++p) { s_[i][p] = 0.f; ss_[i][p] = 0.f; }
    float bb2[8];
#pragma unroll
    for (int j = 0; j < 8; ++j) bb2[j] = b2[128 * wc + 16 * j + r];
#pragma unroll
    for (int i = 0; i < 2; ++i)
#pragma unroll
      for (int p = 0; p < 4; ++p) {
        const int rowl = 32 * wr + 16 * i + 4 * q + p;
#pragma unroll
        for (int j = 0; j < 8; ++j) {
          const int col = 128 * wc + 16 * j + r;
          float v = acc3[i][j][p] + bb2[j] + (float)lX[alay(rowl, col)];
          acc3[i][j][p] = v;
          s_[i][p] += v;
          ss_[i][p] += v * v;
        }
      }
#pragma unroll
    for (int m = 1; m <= 8; m <<= 1)
#pragma unroll
      for (int i = 0; i < 2; ++i)
#pragma unroll
        for (int p = 0; p < 4; ++p) {
          s_[i][p] += __shfl_xor(s_[i][p], m);
          ss_[i][p] += __shfl_xor(ss_[i][p], m);
        }
    __syncthreads();  // rs/rss free for reuse
    if (r == 0) {
#pragma unroll
      for (int i = 0; i < 2; ++i)
#pragma unroll
        for (int p = 0; p < 4; ++p) {
          const int rowl = 32 * wr + 16 * i + 4 * q + p;
          rs[wc][rowl] = s_[i][p];
          rss[wc][rowl] = ss_[i][p];
        }
    }
    __syncthreads();
    float mu[2][4], inv[2][4];
#pragma unroll
    for (int i = 0; i < 2; ++i)
#pragma unroll
      for (int p = 0; p < 4; ++p) {
        const int rowl = 32 * wr + 16 * i + 4 * q + p;
        float tS = rs[0][rowl] + rs[1][rowl] + rs[2][rowl] + rs[3][rowl];
        float tQ = rss[0][rowl] + rss[1][rowl] + rss[2][rowl] + rss[3][rowl];
        float m_ = tS * (1.0f / 512.0f);
        float v_ = tQ * (1.0f / 512.0f) - m_ * m_;
        mu[i][p] = m_;
        inv[i][p] = rsqrtf(v_ + 1e-5f);
      }
    float ga[8], be[8];
#pragma unroll
    for (int j = 0; j < 8; ++j) {
      ga[j] = g2[128 * wc + 16 * j + r];
      be[j] = be2[128 * wc + 16 * j + r];
    }
#pragma unroll
    for (int i = 0; i < 2; ++i)
#pragma unroll
      for (int p = 0; p < 4; ++p) {
        const int rowl = 32 * wr + 16 * i + 4 * q + p;
#pragma unroll
        for (int j = 0; j < 8; ++j) {
          const int col = 128 * wc + 16 * j + r;
          out[(size_t)(m0 + rowl) * 512 + col] =
              (acc3[i][j][p] - mu[i][p]) * inv[i][p] * ga[j] + be[j];
        }
      }
  }
}

extern "C" void kernel_launch(void* const* d_in, const int* in_sizes, int n_in,
                              void* d_out, int out_size, void* d_ws, size_t ws_size,
                              hipStream_t stream) {
  const float* cell = (const float*)d_in[0];
  const float* pert = (const float*)d_in[1];
  const float* Wp   = (const float*)d_in[2];
  const float* bp   = (const float*)d_in[3];
  // d_in[4..7] = Wq,bq,Wk,bk: dead (softmax over a single key == 1 -> attn = v)
  const float* Wv   = (const float*)d_in[8];
  const float* bv   = (const float*)d_in[9];
  const float* Wo   = (const float*)d_in[10];
  const float* bo   = (const float*)d_in[11];
  const float* g1   = (const float*)d_in[12];
  const float* be1  = (const float*)d_in[13];
  const float* g2   = (const float*)d_in[14];
  const float* be2  = (const float*)d_in[15];
  const float* W1   = (const float*)d_in[16];
  const float* b1   = (const float*)d_in[17];
  const float* W2   = (const float*)d_in[18];
  const float* b2   = (const float*)d_in[19];

  char* ws = (char*)d_ws;
  float*  Wvp   = (float*)(ws + 0);          // 512*256*4   = 524288
  float*  bvp   = (float*)(ws + 524288);     // 512*4 (pad) = 2048
  float*  bcomb = (float*)(ws + 526336);     // 512*4 (pad) = 2048
  bf16_t* Wc    = (bf16_t*)(ws + 528384);    // 512*256*2   = 262144 (packed)
  bf16_t* W1b   = (bf16_t*)(ws + 790528);    // 1024*512*2  = 1048576 (packed)
  bf16_t* W2b   = (bf16_t*)(ws + 1839104);   // 512*1024*2  = 1048576 (packed)
  (void)in_sizes; (void)n_in; (void)out_size; (void)ws_size;

  prep_wvp<<<512, 256, 0, stream>>>(Wv, Wp, bp, bv, Wvp, bvp);
  prep_wc<<<512, 256, 0, stream>>>(Wo, bo, Wvp, bvp, Wc, bcomb);
  prep_cast<<<512, 256, 0, stream>>>(W1, W2, W1b, W2b);

  fused_block<<<1024, 512, 0, stream>>>(pert, Wc, bcomb, cell, g1, be1,
                                        W1b, b1, W2b, b2, g2, be2,
                                        (float*)d_out);
}

// Round 11
// 596.191 us; speedup vs baseline: 1.0935x; 1.0546x over previous
//
#include <hip/hip_runtime.h>
#include <hip/hip_bf16.h>

typedef __bf16 bf16_t;
typedef __attribute__((ext_vector_type(8))) __bf16 bf16x8;
typedef __attribute__((ext_vector_type(4))) float f32x4;

// ---------------- prep kernels (tiny, unchanged) ----------------
__global__ void prep_wvp(const float* __restrict__ Wv, const float* __restrict__ Wp,
                         const float* __restrict__ bp, const float* __restrict__ bv,
                         float* __restrict__ Wvp, float* __restrict__ bvp) {
  const int i = blockIdx.x;
  const int j = threadIdx.x;
  float a = 0.f;
  for (int d = 0; d < 512; ++d) a += Wv[i * 512 + d] * Wp[d * 256 + j];
  Wvp[i * 256 + j] = a;
  if (j == 0) {
    float b = 0.f;
    for (int d = 0; d < 512; ++d) b += Wv[i * 512 + d] * bp[d];
    bvp[i] = b + bv[i];
  }
}

// Packed-B layout (harness-verified rounds 4/7/8/9/10), N x K row-major source:
//   B[n][k] -> Bp[(((n>>4)*(K/32) + (k>>5))*64 + ((k>>3)&3)*16 + (n&15))*8 + (k&7)]
__global__ void prep_wc(const float* __restrict__ Wo, const float* __restrict__ bo,
                        const float* __restrict__ Wvp, const float* __restrict__ bvp,
                        bf16_t* __restrict__ Wc, float* __restrict__ bcomb) {
  const int o = blockIdx.x;
  const int j = threadIdx.x;
  float a = 0.f;
  for (int i = 0; i < 512; ++i) a += Wo[o * 512 + i] * Wvp[i * 256 + j];
  const int g = o >> 4, rr = o & 15, t = j >> 5, q = (j >> 3) & 3, e = j & 7;
  Wc[((((size_t)g * 8 + t) * 64) + q * 16 + rr) * 8 + e] = (bf16_t)a;  // S=8
  if (j == 0) {
    float b = 0.f;
    for (int i = 0; i < 512; ++i) b += Wo[o * 512 + i] * bvp[i];
    bcomb[o] = b + bo[o];
  }
}

__global__ void prep_cast(const float* __restrict__ W1, const float* __restrict__ W2,
                          bf16_t* __restrict__ W1b, bf16_t* __restrict__ W2b) {
  const int idx = (blockIdx.x * 256 + threadIdx.x) * 8;
  const float* s;
  bf16_t* d;
  if (idx < 524288) {  // W1: K=512, S=16
    const int o = idx >> 9, k = idx & 511;
    const int g = o >> 4, rr = o & 15, t = k >> 5, q = (k >> 3) & 3;
    s = W1 + idx;
    d = W1b + ((((size_t)g * 16 + t) * 64) + q * 16 + rr) * 8;
  } else {             // W2: K=1024, S=32
    const int i2 = idx - 524288;
    const int o = i2 >> 10, k = i2 & 1023;
    const int g = o >> 4, rr = o & 15, t = k >> 5, q = (k >> 3) & 3;
    s = W2 + i2;
    d = W2b + ((((size_t)g * 32 + t) * 64) + q * 16 + rr) * 8;
  }
  float4 u0 = *(const float4*)s;
  float4 u1 = *(const float4*)(s + 4);
  bf16x8 v;
  v[0] = (bf16_t)u0.x; v[1] = (bf16_t)u0.y; v[2] = (bf16_t)u0.z; v[3] = (bf16_t)u0.w;
  v[4] = (bf16_t)u1.x; v[5] = (bf16_t)u1.y; v[6] = (bf16_t)u1.z; v[7] = (bf16_t)u1.w;
  *(bf16x8*)d = v;
}

// ---------------- fully fused block kernel ----------------
// ROUND-11: round 10 hit the 1-block/CU phase-serialization wall: MFMA busy
// (66us) == MFMA floor, VALU busy 91us, but phases alternate instead of
// overlapping (357us). Fix: 32-row blocks, 256 thr / 4 waves, LDS 48KB ->
// TWO independent blocks/CU. Block A's GELU/LN (VALU) overlaps block B's
// kloops (MFMA). Per-wave economics unchanged (acc[2][8], 512B B-frags per
// MFMA); total B traffic unchanged (dropping the wr-duplication exactly
// offsets 2x block count). LN scratch aliased into lH (dead there).
//
// Phases: P0 pert->lH | P1 attn K=256 ->LN1-> lX | 4x { P2q h_q=gelu(x@W1q)
// ->lH ; P3q acc3 += h_q@W2q } | P4 LN2 -> out.

// A-layout for 32-row tiles: 16-row windows of 1KB; window = (k>>5)*2+(row>>4);
// 16B slot within window = rr*4 + (chunk ^ ((rr>>1)&3)) (verified conflict-free).
__device__ __forceinline__ int alay(int row, int k) {
  const int rr = row & 15;
  const int c = (k >> 3) & 3;
  return ((k >> 5) * 2 + (row >> 4)) * 512 +
         (rr * 4 + (c ^ ((rr >> 1) & 3))) * 8 + (k & 7);
}

template <int STEPS, int NJ>
__device__ __forceinline__ void kloop(const bf16_t* __restrict__ lA_,
                                      const bf16_t* __restrict__ Bp,
                                      int g0, int SB, int soff,
                                      int fRd, int lane,
                                      f32x4 (&acc)[2][NJ]) {
  constexpr int H = NJ / 2;
  auto bfrag = [&](int j, int s) {
    return *(const bf16x8*)(Bp + ((size_t)((g0 + j) * SB + (soff + s)) * 64 + lane) * 8);
  };
  bf16x8 bA[H], bB[H];
#pragma unroll
  for (int j = 0; j < H; ++j) bA[j] = bfrag(j, 0);
#pragma unroll 2
  for (int s = 0; s < STEPS; ++s) {
#pragma unroll
    for (int j = 0; j < H; ++j) bB[j] = bfrag(H + j, s);
    bf16x8 af[2];
#pragma unroll
    for (int i = 0; i < 2; ++i)
      af[i] = *(const bf16x8*)&lA_[(s * 2 + i) * 512 + fRd];
    __builtin_amdgcn_s_setprio(1);
#pragma unroll
    for (int j = 0; j < H; ++j)
#pragma unroll
      for (int i = 0; i < 2; ++i)
        acc[i][j] = __builtin_amdgcn_mfma_f32_16x16x32_bf16(af[i], bA[j], acc[i][j], 0, 0, 0);
    __builtin_amdgcn_s_setprio(0);
    if (s + 1 < STEPS) {
#pragma unroll
      for (int j = 0; j < H; ++j) bA[j] = bfrag(j, s + 1);
    }
    __builtin_amdgcn_s_setprio(1);
#pragma unroll
    for (int j = 0; j < H; ++j)
#pragma unroll
      for (int i = 0; i < 2; ++i)
        acc[i][H + j] = __builtin_amdgcn_mfma_f32_16x16x32_bf16(af[i], bB[j], acc[i][H + j], 0, 0, 0);
    __builtin_amdgcn_s_setprio(0);
  }
}

__global__ __launch_bounds__(256, 2) void fused_block(
    const float* __restrict__ pert, const bf16_t* __restrict__ Wc,
    const float* __restrict__ bcomb, const float* __restrict__ cell,
    const float* __restrict__ g1, const float* __restrict__ be1,
    const bf16_t* __restrict__ W1b, const float* __restrict__ b1,
    const bf16_t* __restrict__ W2b, const float* __restrict__ b2,
    const float* __restrict__ g2, const float* __restrict__ be2,
    float* __restrict__ out) {

  __shared__ __align__(16) bf16_t lX[32 * 512];   // 32 KB: x (A-layout, K=512)
  __shared__ __align__(16) bf16_t lH[32 * 256];   // 16 KB: pert, then h quarters
  // LN scratch aliased into lH (pert/h dead at both LN points)
  float* rsP = (float*)lH;          // rs[4][32]  = 512 B
  float* ssP = (float*)lH + 128;    // rss[4][32] = 512 B

  const int t = threadIdx.x;
  const int m0 = blockIdx.x * 32;
  const int lane = t & 63;
  const int wc = t >> 6;          // wave 0..3 = col quarter; all 32 rows
  const int r = lane & 15;
  const int q = lane >> 4;
  const int qs = q ^ ((r >> 1) & 3);
  const int fRd = r * 32 + qs * 8;

  // ---- P0: stage pert (32 x 256 fp32 -> bf16, A-layout) into lH ----
#pragma unroll
  for (int u = 0; u < 4; ++u) {
    const int g = u * 256 + t;      // slot 0..1023
    const int row = g >> 5;
    const int c = g & 31;
    const float* src = pert + (size_t)(m0 + row) * 256 + c * 8;
    float4 u0 = *(const float4*)src;
    float4 u1 = *(const float4*)(src + 4);
    bf16x8 v;
    v[0] = (bf16_t)u0.x; v[1] = (bf16_t)u0.y; v[2] = (bf16_t)u0.z; v[3] = (bf16_t)u0.w;
    v[4] = (bf16_t)u1.x; v[5] = (bf16_t)u1.y; v[6] = (bf16_t)u1.z; v[7] = (bf16_t)u1.w;
    *(bf16x8*)&lH[alay(row, c * 8)] = v;
  }
  __syncthreads();

  // ---- P1: attn GEMM (K=256), wave cols [128wc,+128) ----
  {
    f32x4 acc1[2][8];
#pragma unroll
    for (int i = 0; i < 2; ++i)
#pragma unroll
      for (int j = 0; j < 8; ++j)
#pragma unroll
        for (int p = 0; p < 4; ++p) acc1[i][j][p] = 0.f;
    kloop<8, 8>(lH, Wc, 8 * wc, 8, 0, fRd, lane, acc1);

    float s_[2][4], ss_[2][4];
#pragma unroll
    for (int i = 0; i < 2; ++i)
#pragma unroll
      for (int p = 0; p < 4; ++p) { s_[i][p] = 0.f; ss_[i][p] = 0.f; }
    float bb[8];
#pragma unroll
    for (int j = 0; j < 8; ++j) bb[j] = bcomb[128 * wc + 16 * j + r];
#pragma unroll
    for (int i = 0; i < 2; ++i)
#pragma unroll
      for (int p = 0; p < 4; ++p) {
        const int rowl = 16 * i + 4 * q + p;
#pragma unroll
        for (int j = 0; j < 8; ++j) {
          const int col = 128 * wc + 16 * j + r;
          float v = acc1[i][j][p] + bb[j] + cell[(size_t)(m0 + rowl) * 512 + col];
          acc1[i][j][p] = v;
          s_[i][p] += v;
          ss_[i][p] += v * v;
        }
      }
#pragma unroll
    for (int m = 1; m <= 8; m <<= 1)
#pragma unroll
      for (int i = 0; i < 2; ++i)
#pragma unroll
        for (int p = 0; p < 4; ++p) {
          s_[i][p] += __shfl_xor(s_[i][p], m);
          ss_[i][p] += __shfl_xor(ss_[i][p], m);
        }
    __syncthreads();  // all waves past kloop(lH) before aliased scratch write
    if (r == 0) {
#pragma unroll
      for (int i = 0; i < 2; ++i)
#pragma unroll
        for (int p = 0; p < 4; ++p) {
          const int rowl = 16 * i + 4 * q + p;
          rsP[wc * 32 + rowl] = s_[i][p];
          ssP[wc * 32 + rowl] = ss_[i][p];
        }
    }
    __syncthreads();
    float mu[2][4], inv[2][4];
#pragma unroll
    for (int i = 0; i < 2; ++i)
#pragma unroll
      for (int p = 0; p < 4; ++p) {
        const int rowl = 16 * i + 4 * q + p;
        float tS = rsP[rowl] + rsP[32 + rowl] + rsP[64 + rowl] + rsP[96 + rowl];
        float tQ = ssP[rowl] + ssP[32 + rowl] + ssP[64 + rowl] + ssP[96 + rowl];
        float m_ = tS * (1.0f / 512.0f);
        float v_ = tQ * (1.0f / 512.0f) - m_ * m_;
        mu[i][p] = m_;
        inv[i][p] = rsqrtf(v_ + 1e-5f);
      }
    float ga[8], be[8];
#pragma unroll
    for (int j = 0; j < 8; ++j) {
      ga[j] = g1[128 * wc + 16 * j + r];
      be[j] = be1[128 * wc + 16 * j + r];
    }
#pragma unroll
    for (int i = 0; i < 2; ++i)
#pragma unroll
      for (int p = 0; p < 4; ++p) {
        const int rowl = 16 * i + 4 * q + p;
#pragma unroll
        for (int j = 0; j < 8; ++j) {
          const int col = 128 * wc + 16 * j + r;
          float v = (acc1[i][j][p] - mu[i][p]) * inv[i][p] * ga[j] + be[j];
          lX[alay(rowl, col)] = (bf16_t)v;
        }
      }
  }
  __syncthreads();  // x resident; lH (pert + scratch) dead

  // ---- FFN: four 256-col h-quarters ----
  f32x4 acc3[2][8];
#pragma unroll
  for (int i = 0; i < 2; ++i)
#pragma unroll
    for (int j = 0; j < 8; ++j)
#pragma unroll
      for (int p = 0; p < 4; ++p) acc3[i][j][p] = 0.f;

  for (int qh = 0; qh < 4; ++qh) {
    {
      f32x4 accq[2][4];
#pragma unroll
      for (int i = 0; i < 2; ++i)
#pragma unroll
        for (int j = 0; j < 4; ++j)
#pragma unroll
          for (int p = 0; p < 4; ++p) accq[i][j][p] = 0.f;
      // P2q: h_q = x @ W1[256qh : +256]^T  (K=512; wave cols [64wc,+64))
      kloop<16, 4>(lX, W1b, 16 * qh + 4 * wc, 16, 0, fRd, lane, accq);
      float bb1[4];
#pragma unroll
      for (int j = 0; j < 4; ++j) bb1[j] = b1[256 * qh + 64 * wc + 16 * j + r];
#pragma unroll
      for (int i = 0; i < 2; ++i)
#pragma unroll
        for (int p = 0; p < 4; ++p) {
          const int rowl = 16 * i + 4 * q + p;
#pragma unroll
          for (int j = 0; j < 4; ++j) {
            const int col = 64 * wc + 16 * j + r;
            float v = accq[i][j][p] + bb1[j];
            float g = 0.5f * v * (1.0f + erff(v * 0.70710678118654752f));
            lH[alay(rowl, col)] = (bf16_t)g;
          }
        }
    }
    __syncthreads();  // h_q resident everywhere
    // P3q: acc3 += h_q @ W2[:, 256qh : +256]^T  (K=256)
    kloop<8, 8>(lH, W2b, 8 * wc, 32, 8 * qh, fRd, lane, acc3);
    __syncthreads();  // all reads of h_q done before overwrite
  }

  // ---- P4: LN2(acc3 + b2 + x) -> fp32 out ----
  {
    float s_[2][4], ss_[2][4];
#pragma unroll
    for (int i = 0; i < 2; ++i)
#pragma unroll
      for (int p = 0; p < 4; ++p) { s_[i][p] = 0.f; ss_[i][p] = 0.f; }
    float bb2[8];
#pragma unroll
    for (int j = 0; j < 8; ++j) bb2[j] = b2[128 * wc + 16 * j + r];
#pragma unroll
    for (int i = 0; i < 2; ++i)
#pragma unroll
      for (int p = 0; p < 4; ++p) {
        const int rowl = 16 * i + 4 * q + p;
#pragma unroll
        for (int j = 0; j < 8; ++j) {
          const int col = 128 * wc + 16 * j + r;
          float v = acc3[i][j][p] + bb2[j] + (float)lX[alay(rowl, col)];
          acc3[i][j][p] = v;
          s_[i][p] += v;
          ss_[i][p] += v * v;
        }
      }
#pragma unroll
    for (int m = 1; m <= 8; m <<= 1)
#pragma unroll
      for (int i = 0; i < 2; ++i)
#pragma unroll
        for (int p = 0; p < 4; ++p) {
          s_[i][p] += __shfl_xor(s_[i][p], m);
          ss_[i][p] += __shfl_xor(ss_[i][p], m);
        }
    // last lH readers done at loop-end barrier; scratch write is safe
    if (r == 0) {
#pragma unroll
      for (int i = 0; i < 2; ++i)
#pragma unroll
        for (int p = 0; p < 4; ++p) {
          const int rowl = 16 * i + 4 * q + p;
          rsP[wc * 32 + rowl] = s_[i][p];
          ssP[wc * 32 + rowl] = ss_[i][p];
        }
    }
    __syncthreads();
    float mu[2][4], inv[2][4];
#pragma unroll
    for (int i = 0; i < 2; ++i)
#pragma unroll
      for (int p = 0; p < 4; ++p) {
        const int rowl = 16 * i + 4 * q + p;
        float tS = rsP[rowl] + rsP[32 + rowl] + rsP[64 + rowl] + rsP[96 + rowl];
        float tQ = ssP[rowl] + ssP[32 + rowl] + ssP[64 + rowl] + ssP[96 + rowl];
        float m_ = tS * (1.0f / 512.0f);
        float v_ = tQ * (1.0f / 512.0f) - m_ * m_;
        mu[i][p] = m_;
        inv[i][p] = rsqrtf(v_ + 1e-5f);
      }
    float ga[8], be[8];
#pragma unroll
    for (int j = 0; j < 8; ++j) {
      ga[j] = g2[128 * wc + 16 * j + r];
      be[j] = be2[128 * wc + 16 * j + r];
    }
#pragma unroll
    for (int i = 0; i < 2; ++i)
#pragma unroll
      for (int p = 0; p < 4; ++p) {
        const int rowl = 16 * i + 4 * q + p;
#pragma unroll
        for (int j = 0; j < 8; ++j) {
          const int col = 128 * wc + 16 * j + r;
          out[(size_t)(m0 + rowl) * 512 + col] =
              (acc3[i][j][p] - mu[i][p]) * inv[i][p] * ga[j] + be[j];
        }
      }
  }
}

extern "C" void kernel_launch(void* const* d_in, const int* in_sizes, int n_in,
                              void* d_out, int out_size, void* d_ws, size_t ws_size,
                              hipStream_t stream) {
  const float* cell = (const float*)d_in[0];
  const float* pert = (const float*)d_in[1];
  const float* Wp   = (const float*)d_in[2];
  const float* bp   = (const float*)d_in[3];
  // d_in[4..7] = Wq,bq,Wk,bk: dead (softmax over a single key == 1 -> attn = v)
  const float* Wv   = (const float*)d_in[8];
  const float* bv   = (const float*)d_in[9];
  const float* Wo   = (const float*)d_in[10];
  const float* bo   = (const float*)d_in[11];
  const float* g1   = (const float*)d_in[12];
  const float* be1  = (const float*)d_in[13];
  const float* g2   = (const float*)d_in[14];
  const float* be2  = (const float*)d_in[15];
  const float* W1   = (const float*)d_in[16];
  const float* b1   = (const float*)d_in[17];
  const float* W2   = (const float*)d_in[18];
  const float* b2   = (const float*)d_in[19];

  char* ws = (char*)d_ws;
  float*  Wvp   = (float*)(ws + 0);          // 512*256*4   = 524288
  float*  bvp   = (float*)(ws + 524288);     // 512*4 (pad) = 2048
  float*  bcomb = (float*)(ws + 526336);     // 512*4 (pad) = 2048
  bf16_t* Wc    = (bf16_t*)(ws + 528384);    // 512*256*2   = 262144 (packed)
  bf16_t* W1b   = (bf16_t*)(ws + 790528);    // 1024*512*2  = 1048576 (packed)
  bf16_t* W2b   = (bf16_t*)(ws + 1839104);   // 512*1024*2  = 1048576 (packed)
  (void)in_sizes; (void)n_in; (void)out_size; (void)ws_size;

  prep_wvp<<<512, 256, 0, stream>>>(Wv, Wp, bp, bv, Wvp, bvp);
  prep_wc<<<512, 256, 0, stream>>>(Wo, bo, Wvp, bvp, Wc, bcomb);
  prep_cast<<<512, 256, 0, stream>>>(W1, W2, W1b, W2b);

  fused_block<<<2048, 256, 0, stream>>>(pert, Wc, bcomb, cell, g1, be1,
                                        W1b, b1, W2b, b2, g2, be2,
                                        (float*)d_out);
}

// Round 12
// 570.748 us; speedup vs baseline: 1.1422x; 1.0446x over previous
//
#include <hip/hip_runtime.h>
#include <hip/hip_bf16.h>

typedef __bf16 bf16_t;
typedef __attribute__((ext_vector_type(8))) __bf16 bf16x8;
typedef __attribute__((ext_vector_type(4))) float f32x4;

// ---------------- prep kernels (tiny, unchanged) ----------------
__global__ void prep_wvp(const float* __restrict__ Wv, const float* __restrict__ Wp,
                         const float* __restrict__ bp, const float* __restrict__ bv,
                         float* __restrict__ Wvp, float* __restrict__ bvp) {
  const int i = blockIdx.x;
  const int j = threadIdx.x;
  float a = 0.f;
  for (int d = 0; d < 512; ++d) a += Wv[i * 512 + d] * Wp[d * 256 + j];
  Wvp[i * 256 + j] = a;
  if (j == 0) {
    float b = 0.f;
    for (int d = 0; d < 512; ++d) b += Wv[i * 512 + d] * bp[d];
    bvp[i] = b + bv[i];
  }
}

// Packed-B layout (harness-verified rounds 4/7/8/9/10/11), N x K row-major source:
//   B[n][k] -> Bp[(((n>>4)*(K/32) + (k>>5))*64 + ((k>>3)&3)*16 + (n&15))*8 + (k&7)]
__global__ void prep_wc(const float* __restrict__ Wo, const float* __restrict__ bo,
                        const float* __restrict__ Wvp, const float* __restrict__ bvp,
                        bf16_t* __restrict__ Wc, float* __restrict__ bcomb) {
  const int o = blockIdx.x;
  const int j = threadIdx.x;
  float a = 0.f;
  for (int i = 0; i < 512; ++i) a += Wo[o * 512 + i] * Wvp[i * 256 + j];
  const int g = o >> 4, rr = o & 15, t = j >> 5, q = (j >> 3) & 3, e = j & 7;
  Wc[((((size_t)g * 8 + t) * 64) + q * 16 + rr) * 8 + e] = (bf16_t)a;  // S=8
  if (j == 0) {
    float b = 0.f;
    for (int i = 0; i < 512; ++i) b += Wo[o * 512 + i] * bvp[i];
    bcomb[o] = b + bo[o];
  }
}

__global__ void prep_cast(const float* __restrict__ W1, const float* __restrict__ W2,
                          bf16_t* __restrict__ W1b, bf16_t* __restrict__ W2b) {
  const int idx = (blockIdx.x * 256 + threadIdx.x) * 8;
  const float* s;
  bf16_t* d;
  if (idx < 524288) {  // W1: K=512, S=16
    const int o = idx >> 9, k = idx & 511;
    const int g = o >> 4, rr = o & 15, t = k >> 5, q = (k >> 3) & 3;
    s = W1 + idx;
    d = W1b + ((((size_t)g * 16 + t) * 64) + q * 16 + rr) * 8;
  } else {             // W2: K=1024, S=32
    const int i2 = idx - 524288;
    const int o = i2 >> 10, k = i2 & 1023;
    const int g = o >> 4, rr = o & 15, t = k >> 5, q = (k >> 3) & 3;
    s = W2 + i2;
    d = W2b + ((((size_t)g * 32 + t) * 64) + q * 16 + rr) * 8;
  }
  float4 u0 = *(const float4*)s;
  float4 u1 = *(const float4*)(s + 4);
  bf16x8 v;
  v[0] = (bf16_t)u0.x; v[1] = (bf16_t)u0.y; v[2] = (bf16_t)u0.z; v[3] = (bf16_t)u0.w;
  v[4] = (bf16_t)u1.x; v[5] = (bf16_t)u1.y; v[6] = (bf16_t)u1.z; v[7] = (bf16_t)u1.w;
  *(bf16x8*)d = v;
}

// ---------------- fully fused block kernel ----------------
// ROUND-12: round 11 profile: traffic ideal (136/133 MB), MFMA busy 67us,
// VALU 87us, but dur 330us -- ~175us of exposed operand latency: kloop
// consumed bB ~50cyc after its L2 issue (~200cyc lat) and af directly after
// its ds_read (~120cyc lat), stalling ~300cyc/step vs 160cyc compute.
// Fix (T14 at register level): FULL-STEP software pipeline -- during step s's
// 16 MFMAs, issue ALL of step s+1's B global-loads and A ds_reads into
// bNxt/aNxt; consume next step. Prefetch distance > both latencies.
// +40 VGPR worst-phase (~175 total) stays under the 2-wave/SIMD cap.
//
// Phases: P0 pert->lH | P1 attn K=256 ->LN1-> lX | 4x { P2q h_q=gelu(x@W1q)
// ->lH ; P3q acc3 += h_q@W2q } | P4 LN2 -> out.

// A-layout for 32-row tiles: 16-row windows of 1KB; window = (k>>5)*2+(row>>4);
// 16B slot within window = rr*4 + (chunk ^ ((rr>>1)&3)) (verified conflict-free).
__device__ __forceinline__ int alay(int row, int k) {
  const int rr = row & 15;
  const int c = (k >> 3) & 3;
  return ((k >> 5) * 2 + (row >> 4)) * 512 +
         (rr * 4 + (c ^ ((rr >> 1) & 3))) * 8 + (k & 7);
}

template <int STEPS, int NJ>
__device__ __forceinline__ void kloop(const bf16_t* __restrict__ lA_,
                                      const bf16_t* __restrict__ Bp,
                                      int g0, int SB, int soff,
                                      int fRd, int lane,
                                      f32x4 (&acc)[2][NJ]) {
  auto bfrag = [&](int j, int s) {
    return *(const bf16x8*)(Bp + ((size_t)((g0 + j) * SB + (soff + s)) * 64 + lane) * 8);
  };
  auto afrag = [&](int i, int s) {
    return *(const bf16x8*)&lA_[(s * 2 + i) * 512 + fRd];
  };
  bf16x8 bCur[NJ], bNxt[NJ], aCur[2], aNxt[2];
#pragma unroll
  for (int j = 0; j < NJ; ++j) bCur[j] = bfrag(j, 0);
#pragma unroll
  for (int i = 0; i < 2; ++i) aCur[i] = afrag(i, 0);
#pragma unroll
  for (int s = 0; s < STEPS; ++s) {
    // issue next step's operand loads BEFORE this step's MFMAs (full-step
    // prefetch: L2 ~200cyc and LDS ~120cyc hide under 16 MFMAs + co-block)
    if (s + 1 < STEPS) {
#pragma unroll
      for (int j = 0; j < NJ; ++j) bNxt[j] = bfrag(j, s + 1);
#pragma unroll
      for (int i = 0; i < 2; ++i) aNxt[i] = afrag(i, s + 1);
    }
    __builtin_amdgcn_s_setprio(1);
#pragma unroll
    for (int j = 0; j < NJ; ++j)
#pragma unroll
      for (int i = 0; i < 2; ++i)
        acc[i][j] = __builtin_amdgcn_mfma_f32_16x16x32_bf16(aCur[i], bCur[j], acc[i][j], 0, 0, 0);
    __builtin_amdgcn_s_setprio(0);
    // SSA-renamed away under full unroll
#pragma unroll
    for (int j = 0; j < NJ; ++j) bCur[j] = bNxt[j];
#pragma unroll
    for (int i = 0; i < 2; ++i) aCur[i] = aNxt[i];
  }
}

__global__ __launch_bounds__(256, 2) void fused_block(
    const float* __restrict__ pert, const bf16_t* __restrict__ Wc,
    const float* __restrict__ bcomb, const float* __restrict__ cell,
    const float* __restrict__ g1, const float* __restrict__ be1,
    const bf16_t* __restrict__ W1b, const float* __restrict__ b1,
    const bf16_t* __restrict__ W2b, const float* __restrict__ b2,
    const float* __restrict__ g2, const float* __restrict__ be2,
    float* __restrict__ out) {

  __shared__ __align__(16) bf16_t lX[32 * 512];   // 32 KB: x (A-layout, K=512)
  __shared__ __align__(16) bf16_t lH[32 * 256];   // 16 KB: pert, then h quarters
  // LN scratch aliased into lH (pert/h dead at both LN points)
  float* rsP = (float*)lH;          // rs[4][32]  = 512 B
  float* ssP = (float*)lH + 128;    // rss[4][32] = 512 B

  const int t = threadIdx.x;
  const int m0 = blockIdx.x * 32;
  const int lane = t & 63;
  const int wc = t >> 6;          // wave 0..3 = col quarter; all 32 rows
  const int r = lane & 15;
  const int q = lane >> 4;
  const int qs = q ^ ((r >> 1) & 3);
  const int fRd = r * 32 + qs * 8;

  // ---- P0: stage pert (32 x 256 fp32 -> bf16, A-layout) into lH ----
#pragma unroll
  for (int u = 0; u < 4; ++u) {
    const int g = u * 256 + t;      // slot 0..1023
    const int row = g >> 5;
    const int c = g & 31;
    const float* src = pert + (size_t)(m0 + row) * 256 + c * 8;
    float4 u0 = *(const float4*)src;
    float4 u1 = *(const float4*)(src + 4);
    bf16x8 v;
    v[0] = (bf16_t)u0.x; v[1] = (bf16_t)u0.y; v[2] = (bf16_t)u0.z; v[3] = (bf16_t)u0.w;
    v[4] = (bf16_t)u1.x; v[5] = (bf16_t)u1.y; v[6] = (bf16_t)u1.z; v[7] = (bf16_t)u1.w;
    *(bf16x8*)&lH[alay(row, c * 8)] = v;
  }
  __syncthreads();

  // ---- P1: attn GEMM (K=256), wave cols [128wc,+128) ----
  {
    f32x4 acc1[2][8];
#pragma unroll
    for (int i = 0; i < 2; ++i)
#pragma unroll
      for (int j = 0; j < 8; ++j)
#pragma unroll
        for (int p = 0; p < 4; ++p) acc1[i][j][p] = 0.f;
    kloop<8, 8>(lH, Wc, 8 * wc, 8, 0, fRd, lane, acc1);

    float s_[2][4], ss_[2][4];
#pragma unroll
    for (int i = 0; i < 2; ++i)
#pragma unroll
      for (int p = 0; p < 4; ++p) { s_[i][p] = 0.f; ss_[i][p] = 0.f; }
    float bb[8];
#pragma unroll
    for (int j = 0; j < 8; ++j) bb[j] = bcomb[128 * wc + 16 * j + r];
#pragma unroll
    for (int i = 0; i < 2; ++i)
#pragma unroll
      for (int p = 0; p < 4; ++p) {
        const int rowl = 16 * i + 4 * q + p;
#pragma unroll
        for (int j = 0; j < 8; ++j) {
          const int col = 128 * wc + 16 * j + r;
          float v = acc1[i][j][p] + bb[j] + cell[(size_t)(m0 + rowl) * 512 + col];
          acc1[i][j][p] = v;
          s_[i][p] += v;
          ss_[i][p] += v * v;
        }
      }
#pragma unroll
    for (int m = 1; m <= 8; m <<= 1)
#pragma unroll
      for (int i = 0; i < 2; ++i)
#pragma unroll
        for (int p = 0; p < 4; ++p) {
          s_[i][p] += __shfl_xor(s_[i][p], m);
          ss_[i][p] += __shfl_xor(ss_[i][p], m);
        }
    __syncthreads();  // all waves past kloop(lH) before aliased scratch write
    if (r == 0) {
#pragma unroll
      for (int i = 0; i < 2; ++i)
#pragma unroll
        for (int p = 0; p < 4; ++p) {
          const int rowl = 16 * i + 4 * q + p;
          rsP[wc * 32 + rowl] = s_[i][p];
          ssP[wc * 32 + rowl] = ss_[i][p];
        }
    }
    __syncthreads();
    float mu[2][4], inv[2][4];
#pragma unroll
    for (int i = 0; i < 2; ++i)
#pragma unroll
      for (int p = 0; p < 4; ++p) {
        const int rowl = 16 * i + 4 * q + p;
        float tS = rsP[rowl] + rsP[32 + rowl] + rsP[64 + rowl] + rsP[96 + rowl];
        float tQ = ssP[rowl] + ssP[32 + rowl] + ssP[64 + rowl] + ssP[96 + rowl];
        float m_ = tS * (1.0f / 512.0f);
        float v_ = tQ * (1.0f / 512.0f) - m_ * m_;
        mu[i][p] = m_;
        inv[i][p] = rsqrtf(v_ + 1e-5f);
      }
    float ga[8], be[8];
#pragma unroll
    for (int j = 0; j < 8; ++j) {
      ga[j] = g1[128 * wc + 16 * j + r];
      be[j] = be1[128 * wc + 16 * j + r];
    }
#pragma unroll
    for (int i = 0; i < 2; ++i)
#pragma unroll
      for (int p = 0; p < 4; ++p) {
        const int rowl = 16 * i + 4 * q + p;
#pragma unroll
        for (int j = 0; j < 8; ++j) {
          const int col = 128 * wc + 16 * j + r;
          float v = (acc1[i][j][p] - mu[i][p]) * inv[i][p] * ga[j] + be[j];
          lX[alay(rowl, col)] = (bf16_t)v;
        }
      }
  }
  __syncthreads();  // x resident; lH (pert + scratch) dead

  // ---- FFN: four 256-col h-quarters ----
  f32x4 acc3[2][8];
#pragma unroll
  for (int i = 0; i < 2; ++i)
#pragma unroll
    for (int j = 0; j < 8; ++j)
#pragma unroll
      for (int p = 0; p < 4; ++p) acc3[i][j][p] = 0.f;

  for (int qh = 0; qh < 4; ++qh) {
    {
      f32x4 accq[2][4];
#pragma unroll
      for (int i = 0; i < 2; ++i)
#pragma unroll
        for (int j = 0; j < 4; ++j)
#pragma unroll
          for (int p = 0; p < 4; ++p) accq[i][j][p] = 0.f;
      // P2q: h_q = x @ W1[256qh : +256]^T  (K=512; wave cols [64wc,+64))
      kloop<16, 4>(lX, W1b, 16 * qh + 4 * wc, 16, 0, fRd, lane, accq);
      float bb1[4];
#pragma unroll
      for (int j = 0; j < 4; ++j) bb1[j] = b1[256 * qh + 64 * wc + 16 * j + r];
#pragma unroll
      for (int i = 0; i < 2; ++i)
#pragma unroll
        for (int p = 0; p < 4; ++p) {
          const int rowl = 16 * i + 4 * q + p;
#pragma unroll
          for (int j = 0; j < 4; ++j) {
            const int col = 64 * wc + 16 * j + r;
            float v = accq[i][j][p] + bb1[j];
            float g = 0.5f * v * (1.0f + erff(v * 0.70710678118654752f));
            lH[alay(rowl, col)] = (bf16_t)g;
          }
        }
    }
    __syncthreads();  // h_q resident everywhere
    // P3q: acc3 += h_q @ W2[:, 256qh : +256]^T  (K=256)
    kloop<8, 8>(lH, W2b, 8 * wc, 32, 8 * qh, fRd, lane, acc3);
    __syncthreads();  // all reads of h_q done before overwrite
  }

  // ---- P4: LN2(acc3 + b2 + x) -> fp32 out ----
  {
    float s_[2][4], ss_[2][4];
#pragma unroll
    for (int i = 0; i < 2; ++i)
#pragma unroll
      for (int p = 0; p < 4; ++p) { s_[i][p] = 0.f; ss_[i][p] = 0.f; }
    float bb2[8];
#pragma unroll
    for (int j = 0; j < 8; ++j) bb2[j] = b2[128 * wc + 16 * j + r];
#pragma unroll
    for (int i = 0; i < 2; ++i)
#pragma unroll
      for (int p = 0; p < 4; ++p) {
        const int rowl = 16 * i + 4 * q + p;
#pragma unroll
        for (int j = 0; j < 8; ++j) {
          const int col = 128 * wc + 16 * j + r;
          float v = acc3[i][j][p] + bb2[j] + (float)lX[alay(rowl, col)];
          acc3[i][j][p] = v;
          s_[i][p] += v;
          ss_[i][p] += v * v;
        }
      }
#pragma unroll
    for (int m = 1; m <= 8; m <<= 1)
#pragma unroll
      for (int i = 0; i < 2; ++i)
#pragma unroll
        for (int p = 0; p < 4; ++p) {
          s_[i][p] += __shfl_xor(s_[i][p], m);
          ss_[i][p] += __shfl_xor(ss_[i][p], m);
        }
    // last lH readers done at loop-end barrier; scratch write is safe
    if (r == 0) {
#pragma unroll
      for (int i = 0; i < 2; ++i)
#pragma unroll
        for (int p = 0; p < 4; ++p) {
          const int rowl = 16 * i + 4 * q + p;
          rsP[wc * 32 + rowl] = s_[i][p];
          ssP[wc * 32 + rowl] = ss_[i][p];
        }
    }
    __syncthreads();
    float mu[2][4], inv[2][4];
#pragma unroll
    for (int i = 0; i < 2; ++i)
#pragma unroll
      for (int p = 0; p < 4; ++p) {
        const int rowl = 16 * i + 4 * q + p;
        float tS = rsP[rowl] + rsP[32 + rowl] + rsP[64 + rowl] + rsP[96 + rowl];
        float tQ = ssP[rowl] + ssP[32 + rowl] + ssP[64 + rowl] + ssP[96 + rowl];
        float m_ = tS * (1.0f / 512.0f);
        float v_ = tQ * (1.0f / 512.0f) - m_ * m_;
        mu[i][p] = m_;
        inv[i][p] = rsqrtf(v_ + 1e-5f);
      }
    float ga[8], be[8];
#pragma unroll
    for (int j = 0; j < 8; ++j) {
      ga[j] = g2[128 * wc + 16 * j + r];
      be[j] = be2[128 * wc + 16 * j + r];
    }
#pragma unroll
    for (int i = 0; i < 2; ++i)
#pragma unroll
      for (int p = 0; p < 4; ++p) {
        const int rowl = 16 * i + 4 * q + p;
#pragma unroll
        for (int j = 0; j < 8; ++j) {
          const int col = 128 * wc + 16 * j + r;
          out[(size_t)(m0 + rowl) * 512 + col] =
              (acc3[i][j][p] - mu[i][p]) * inv[i][p] * ga[j] + be[j];
        }
      }
  }
}

extern "C" void kernel_launch(void* const* d_in, const int* in_sizes, int n_in,
                              void* d_out, int out_size, void* d_ws, size_t ws_size,
                              hipStream_t stream) {
  const float* cell = (const float*)d_in[0];
  const float* pert = (const float*)d_in[1];
  const float* Wp   = (const float*)d_in[2];
  const float* bp   = (const float*)d_in[3];
  // d_in[4..7] = Wq,bq,Wk,bk: dead (softmax over a single key == 1 -> attn = v)
  const float* Wv   = (const float*)d_in[8];
  const float* bv   = (const float*)d_in[9];
  const float* Wo   = (const float*)d_in[10];
  const float* bo   = (const float*)d_in[11];
  const float* g1   = (const float*)d_in[12];
  const float* be1  = (const float*)d_in[13];
  const float* g2   = (const float*)d_in[14];
  const float* be2  = (const float*)d_in[15];
  const float* W1   = (const float*)d_in[16];
  const float* b1   = (const float*)d_in[17];
  const float* W2   = (const float*)d_in[18];
  const float* b2   = (const float*)d_in[19];

  char* ws = (char*)d_ws;
  float*  Wvp   = (float*)(ws + 0);          // 512*256*4   = 524288
  float*  bvp   = (float*)(ws + 524288);     // 512*4 (pad) = 2048
  float*  bcomb = (float*)(ws + 526336);     // 512*4 (pad) = 2048
  bf16_t* Wc    = (bf16_t*)(ws + 528384);    // 512*256*2   = 262144 (packed)
  bf16_t* W1b   = (bf16_t*)(ws + 790528);    // 1024*512*2  = 1048576 (packed)
  bf16_t* W2b   = (bf16_t*)(ws + 1839104);   // 512*1024*2  = 1048576 (packed)
  (void)in_sizes; (void)n_in; (void)out_size; (void)ws_size;

  prep_wvp<<<512, 256, 0, stream>>>(Wv, Wp, bp, bv, Wvp, bvp);
  prep_wc<<<512, 256, 0, stream>>>(Wo, bo, Wvp, bvp, Wc, bcomb);
  prep_cast<<<512, 256, 0, stream>>>(W1, W2, W1b, W2b);

  fused_block<<<2048, 256, 0, stream>>>(pert, Wc, bcomb, cell, g1, be1,
                                        W1b, b1, W2b, b2, g2, be2,
                                        (float*)d_out);
}